// Round 1
// baseline (394.852 us; speedup 1.0000x reference)
//
#include <hip/hip_runtime.h>

#define IMG_H 4096
#define IMG_W 6144

constexpr int TILE_W = 128;          // output columns per block
constexpr int TILE_H = 16;           // output rows per block
constexpr int PITCH  = TILE_W + 4;   // 132 (2-col halo each side)
constexpr int LROWS  = TILE_H + 4;   // 20  (2-row halo each side)

// Sparse MHC 5x5 taps, center pointer p into LDS with row pitch PITCH.
__device__ __forceinline__ float convG(const float* p) {       // G at R/B sites
    return ( -p[-2*PITCH] + 2.f*p[-PITCH] + 2.f*p[PITCH] - p[2*PITCH]
             - p[-2] + 2.f*p[-1] + 4.f*p[0] + 2.f*p[1] - p[2] ) * 0.125f;
}
__device__ __forceinline__ float convRrow(const float* p) {    // R at G, R-row (also B at G, B-row)
    return ( 0.5f*(p[-2*PITCH] + p[2*PITCH])
             - (p[-PITCH-1] + p[-PITCH+1] + p[PITCH-1] + p[PITCH+1])
             - (p[-2] + p[2]) + 4.f*(p[-1] + p[1]) + 5.f*p[0] ) * 0.125f;
}
__device__ __forceinline__ float convBrow(const float* p) {    // R at G, B-row (also B at G, R-row)
    return ( -(p[-2*PITCH] + p[2*PITCH])
             - (p[-PITCH-1] + p[-PITCH+1] + p[PITCH-1] + p[PITCH+1])
             + 4.f*(p[-PITCH] + p[PITCH]) + 0.5f*(p[-2] + p[2]) + 5.f*p[0] ) * 0.125f;
}
__device__ __forceinline__ float convRB(const float* p) {      // R at B / B at R
    return ( -1.5f*(p[-2*PITCH] + p[2*PITCH] + p[-2] + p[2])
             + 2.f*(p[-PITCH-1] + p[-PITCH+1] + p[PITCH-1] + p[PITCH+1])
             + 6.f*p[0] ) * 0.125f;
}

__device__ __forceinline__ int clampi(float v) {
    v = fminf(fmaxf(v, 0.f), 16777215.f);
    return (int)v;   // truncate toward zero, same as astype(int32)
}

__global__ __launch_bounds__(256)
void demosaic_kernel(const int* __restrict__ x, int* __restrict__ out) {
    __shared__ float s[LROWS][PITCH];

    const int gx0 = blockIdx.x * TILE_W;
    const int gy0 = blockIdx.y * TILE_H;
    const int tid = threadIdx.x;

    // ---- stage 20x132 input tile into LDS with reflect-by-2 padding ----
    for (int idx = tid; idx < LROWS * PITCH; idx += 256) {
        int r = idx / PITCH;
        int c = idx - r * PITCH;
        int gr = gy0 + r - 2;
        gr = gr < 0 ? -gr : (gr >= IMG_H ? 2 * IMG_H - 2 - gr : gr);
        int gc = gx0 + c - 2;
        gc = gc < 0 ? -gc : (gc >= IMG_W ? 2 * IMG_W - 2 - gc : gc);
        s[r][c] = (float)x[gr * IMG_W + gc];
    }
    __syncthreads();

    const int lane = tid & 63;     // column-pair index within tile
    const int ty   = tid >> 6;     // 0..3
    const int c    = 2 * lane;     // local col of even pixel

    #pragma unroll
    for (int k = 0; k < 4; ++k) {
        const int r  = ty + 4 * k;        // local row 0..15
        const int gi = gy0 + r;           // global row
        const float* pe = &s[r + 2][c + 2];   // center: even column pixel
        const float* po = pe + 1;             // center: odd column pixel

        const float xe = pe[0];
        const float xo = po[0];

        int Re, Ge, Be, Ro, Go, Bo;
        if ((r & 1) == 0) {
            // even row: even col = R site, odd col = G site (R row)
            Re = clampi(xe);
            Ge = clampi(convG(pe));
            Be = clampi(convRB(pe));
            Ro = clampi(convRrow(po));
            Go = clampi(xo);
            Bo = clampi(convBrow(po));
        } else {
            // odd row: even col = G site (B row), odd col = B site
            Re = clampi(convBrow(pe));
            Ge = clampi(xe);
            Be = clampi(convRrow(pe));
            Ro = clampi(convRB(po));
            Go = clampi(convG(po));
            Bo = clampi(xo);
        }

        // 6 contiguous ints: [Re Ge Be Ro Go Bo]; base is even -> 8B aligned
        long base = ((long)gi * IMG_W + (gx0 + c)) * 3;
        int2* o2 = (int2*)(out + base);
        o2[0] = make_int2(Re, Ge);
        o2[1] = make_int2(Be, Ro);
        o2[2] = make_int2(Go, Bo);
    }
}

extern "C" void kernel_launch(void* const* d_in, const int* in_sizes, int n_in,
                              void* d_out, int out_size, void* d_ws, size_t ws_size,
                              hipStream_t stream) {
    const int* x = (const int*)d_in[0];
    int* out = (int*)d_out;
    dim3 grid(IMG_W / TILE_W, IMG_H / TILE_H);   // 48 x 256
    demosaic_kernel<<<grid, 256, 0, stream>>>(x, out);
}

// Round 2
// 360.172 us; speedup vs baseline: 1.0963x; 1.0963x over previous
//
#include <hip/hip_runtime.h>

#define IMG_H 4096
#define IMG_W 6144

constexpr int TILE_W = 128;   // output cols per block
constexpr int TILE_H = 16;    // output rows per block
constexpr int LPAD   = 4;     // interior starts at col 4 -> 16B-aligned float4 stores
constexpr int PITCH  = 136;   // 4 | 128 | 4 (halo lives in cols 2,3 and 132,133)
constexpr int LROWS  = 20;    // 16 + 2x2 halo rows

typedef int i4 __attribute__((ext_vector_type(4)));

__device__ __forceinline__ int reflect_h(int r) {
    return r < 0 ? -r : (r >= IMG_H ? 2 * IMG_H - 2 - r : r);
}
__device__ __forceinline__ int reflect_w(int c) {
    return c < 0 ? -c : (c >= IMG_W ? 2 * IMG_W - 2 - c : c);
}
__device__ __forceinline__ int clampi(float v) {
    return (int)fminf(fmaxf(v, 0.f), 16777215.f);  // truncate == astype(int32)
}

__global__ __launch_bounds__(256)
void demosaic_kernel(const int* __restrict__ x, int* __restrict__ out) {
    // union: input tile (20x136 f32 = 10.88 KB) then output tile (16x384 i32 = 24 KB)
    __shared__ __align__(16) char smem[24576];
    float (*sin_)[PITCH] = (float (*)[PITCH])smem;
    int* sout = (int*)smem;

    const int tid = threadIdx.x;
    const int gx0 = blockIdx.x * TILE_W;
    const int gy0 = blockIdx.y * TILE_H;

    // ---- stage interior: 20 rows x 32 int4 (fully coalesced 16B loads) ----
    #pragma unroll
    for (int it = 0; it < 3; ++it) {
        int idx = tid + it * 256;
        if (idx < LROWS * 32) {
            int r = idx >> 5, v = idx & 31;
            int gr = reflect_h(gy0 + r - 2);
            i4 q = *(const i4*)(x + (long)gr * IMG_W + gx0 + 4 * v);
            float4 f = make_float4((float)q.x, (float)q.y, (float)q.z, (float)q.w);
            *(float4*)&sin_[r][LPAD + 4 * v] = f;
        }
    }
    // ---- halo: 4 cols x 20 rows, scalar ----
    if (tid < 80) {
        int r = tid >> 2, h = tid & 3;
        int gr = reflect_h(gy0 + r - 2);
        int lc = (h < 2) ? (2 + h) : (130 + h);      // 2,3,132,133
        int gc = reflect_w(gx0 + lc - LPAD);
        sin_[r][lc] = (float)x[(long)gr * IMG_W + gc];
    }
    __syncthreads();

    const int p  = tid & 63;     // column-pair index (even col = 2p)
    const int ty = tid >> 6;     // 0..3 ; row parity wave-uniform
    const int cl = LPAD + 2 * p; // local col of even pixel in sin_

    int rr[4][6];

    #pragma unroll
    for (int k = 0; k < 4; ++k) {
        const int r = ty + 4 * k;        // local output row; input tile row = r..r+4
        float w[5][6];
        #pragma unroll
        for (int i = 0; i < 5; ++i) {
            float2 a  = *(const float2*)&sin_[r + i][cl - 2];
            float2 b  = *(const float2*)&sin_[r + i][cl];
            float2 c2 = *(const float2*)&sin_[r + i][cl + 2];
            w[i][0] = a.x;  w[i][1] = a.y;
            w[i][2] = b.x;  w[i][3] = b.y;
            w[i][4] = c2.x; w[i][5] = c2.y;
        }
        const float xe = w[2][2], xo = w[2][3];

        if ((ty & 1) == 0) {
            // even row: even col = R site, odd col = G site (R row)
            float Ge = (-w[0][2] + 2.f*(w[1][2]+w[3][2]) + 4.f*w[2][2] - w[4][2]
                        - w[2][0] + 2.f*(w[2][1]+w[2][3]) - w[2][4]) * 0.125f;
            float Ce = (-1.5f*(w[0][2]+w[4][2]+w[2][0]+w[2][4])
                        + 2.f*(w[1][1]+w[1][3]+w[3][1]+w[3][3]) + 6.f*w[2][2]) * 0.125f;
            float RRo = (0.5f*(w[0][3]+w[4][3]) - (w[1][2]+w[1][4]+w[3][2]+w[3][4])
                         - (w[2][1]+w[2][5]) + 4.f*(w[2][2]+w[2][4]) + 5.f*w[2][3]) * 0.125f;
            float RBo = (-(w[0][3]+w[4][3]) - (w[1][2]+w[1][4]+w[3][2]+w[3][4])
                         + 4.f*(w[1][3]+w[3][3]) + 0.5f*(w[2][1]+w[2][5]) + 5.f*w[2][3]) * 0.125f;
            rr[k][0] = clampi(xe);  rr[k][1] = clampi(Ge);  rr[k][2] = clampi(Ce);
            rr[k][3] = clampi(RRo); rr[k][4] = clampi(xo);  rr[k][5] = clampi(RBo);
        } else {
            // odd row: even col = G site (B row), odd col = B site
            float RBe = (-(w[0][2]+w[4][2]) - (w[1][1]+w[1][3]+w[3][1]+w[3][3])
                         + 4.f*(w[1][2]+w[3][2]) + 0.5f*(w[2][0]+w[2][4]) + 5.f*w[2][2]) * 0.125f;
            float RRe = (0.5f*(w[0][2]+w[4][2]) - (w[1][1]+w[1][3]+w[3][1]+w[3][3])
                         - (w[2][0]+w[2][4]) + 4.f*(w[2][1]+w[2][3]) + 5.f*w[2][2]) * 0.125f;
            float Co  = (-1.5f*(w[0][3]+w[4][3]+w[2][1]+w[2][5])
                         + 2.f*(w[1][2]+w[1][4]+w[3][2]+w[3][4]) + 6.f*w[2][3]) * 0.125f;
            float Go  = (-w[0][3] + 2.f*(w[1][3]+w[3][3]) + 4.f*w[2][3] - w[4][3]
                         - w[2][1] + 2.f*(w[2][2]+w[2][4]) - w[2][5]) * 0.125f;
            rr[k][0] = clampi(RBe); rr[k][1] = clampi(xe);  rr[k][2] = clampi(RRe);
            rr[k][3] = clampi(Co);  rr[k][4] = clampi(Go);  rr[k][5] = clampi(xo);
        }
    }

    __syncthreads();   // done reading sin_; smem becomes output tile

    #pragma unroll
    for (int k = 0; k < 4; ++k) {
        int r = ty + 4 * k;
        int2* o = (int2*)&sout[r * (TILE_W * 3) + 6 * p];   // 8B-aligned
        o[0] = make_int2(rr[k][0], rr[k][1]);
        o[1] = make_int2(rr[k][2], rr[k][3]);
        o[2] = make_int2(rr[k][4], rr[k][5]);
    }
    __syncthreads();

    // ---- coalesced copyout: 16 rows x 96 int4 per block, nontemporal ----
    #pragma unroll
    for (int it = 0; it < 6; ++it) {
        int j = tid + it * 256;                // 0..1535
        i4 q = *(const i4*)&sout[4 * j];
        int r  = j / 96;                       // 96 int4 per tile row
        int wv = j - r * 96;
        int* dst = out + (long)(gy0 + r) * (IMG_W * 3) + gx0 * 3 + 4 * wv;
        __builtin_nontemporal_store(q, (i4*)dst);
    }
}

extern "C" void kernel_launch(void* const* d_in, const int* in_sizes, int n_in,
                              void* d_out, int out_size, void* d_ws, size_t ws_size,
                              hipStream_t stream) {
    const int* x = (const int*)d_in[0];
    int* out = (int*)d_out;
    dim3 grid(IMG_W / TILE_W, IMG_H / TILE_H);   // 48 x 256
    demosaic_kernel<<<grid, 256, 0, stream>>>(x, out);
}